// Round 13
// baseline (218.643 us; speedup 1.0000x reference)
//
#include <hip/hip_runtime.h>
#include <math.h>

// DecoderCell (LFADS) on MI355X — round 13: WAVE-PRIVATE LDS pipeline.
// Rounds 10-12 proved register-destination prefetch is un-forceable at HIP
// level (RA reuses dest regs + inserts WAW waits; VGPR stuck at 64). Fix:
// global_load_lds into per-wave LDS double-buffers (no VGPR dest -> no WAW
// hazard; vmcnt is per-wave -> counted waits, NO barriers, no lockstep).
// Frag layout == gll16's linear lane*16B dest (identity mapping).
// Per step: vmcnt(6) -> 6x ds_read_b128 (contiguous, conflict-free) +
// 8 MFMA -> lgkmcnt(0) -> reissue 6 gll16 into consumed buffer.
//
// PRE pipeline (9 dispatches):
//   pre_hf / pre_wf / pre_fw -> con_rz -> con_n -> co -> gen_rz -> gen_n -> facp
// Scratch liveness (verified rounds 9-12):
//   zC  : out f32 [0:256)   — con_rz(z) -> con_n; dead before gen_rz(z)
//   rhC : out f32 [256:512) frag rows rb*16+kb(0..7)   — con_rz(r) -> con_n
//   cs  : out f32 [256:512) frag rows rb*16+8+kb(0..7) — con_n -> co
//   gi  : out f32 [1152:1280) frag pieces — co -> gen_rz/gen_n; dead before facp
//   zG  : out f32 [0:512)   — gen_rz(z) -> gen_n (same-element read-then-write)
//   rhG : ws panel kb16..31 — gen_rz(r) -> gen_n

#define HD    1280
#define NROW  16384
#define CLIPV 5.0f

typedef float  f32x4  __attribute__((ext_vector_type(4)));
typedef __bf16 bf16x8 __attribute__((ext_vector_type(8)));
typedef short  s16x8  __attribute__((ext_vector_type(8)));
typedef unsigned short u16;

// ws layout (bf16 elems): frag panel [1024 rb][32 kb][64][8] then frag weights.
// panel kbs: hgen 0-15 | hcon 16-23 | factor 24-27 | x 28-31 (16..31 reused as rhG)
#define OFF_CW   16777216              // con wih  frag (48cb x 8kb)
#define OFF_CWH  (OFF_CW  + 196608)    // con whh  frag (48cb x 8kb)
#define OFF_COW  (OFF_CWH + 196608)    // co  w    frag (16cb x 8kb)
#define OFF_GWI  (OFF_COW + 65536)     // gen wih  frag (96cb x 4kb)
#define OFF_GWH  (OFF_GWI + 196608)    // gen whh  frag (96cb x 16kb)
#define OFF_FW   (OFF_GWH + 786432)    // fac w row-major normalized bf16
#define WS_ELEMS (OFF_FW  + 65536)

__device__ __forceinline__ u16 f2bf(float f) {
    unsigned u = __float_as_uint(f);
    u = u + 0x7fffu + ((u >> 16) & 1u);
    return (u16)(u >> 16);
}
__device__ __forceinline__ float sigm(float v) { return 1.0f / (1.0f + __expf(-v)); }

__device__ __forceinline__ int xswz() {
    const int b   = blockIdx.x;
    const int cpx = gridDim.x >> 3;
    return (b & 7) * cpx + (b >> 3);
}

__device__ __forceinline__ void gll16(const void* g, void* l) {
    __builtin_amdgcn_global_load_lds((const __attribute__((address_space(1))) void*)g,
                                     (__attribute__((address_space(3))) void*)l,
                                     16, 0, 0);
}

__device__ __forceinline__ const u16* PF(const u16* ws, int rb, int kb) {
    return ws + (((size_t)(rb * 32 + kb)) << 9);
}

// ---- swizzled LDS tile helpers (epilogue bounce only) -----------------------
__device__ __forceinline__ bf16x8 ldfrag(const char* lds, int r, int ks, int g) {
    const char* p = lds + r * 128 + ((((ks << 2) + g) << 4) ^ ((r & 7) << 4));
    return __builtin_bit_cast(bf16x8, *(const s16x8*)p);
}
__device__ __forceinline__ void ldsw16(char* tile, int r, int kloc, u16 v) {
    const int byte = r * 128 + ((((kloc >> 3) << 4) ^ ((r & 7) << 4)) + ((kloc & 7) << 1));
    *(u16*)(tile + byte) = v;
}

#define MFMA(a, b, c) __builtin_amdgcn_mfma_f32_16x16x32_bf16(a, b, c, 0, 0, 0)

#define GIDX                                                                  \
    const int l  = threadIdx.x & 63;                                          \
    const int w  = threadIdx.x >> 6;                                          \
    const int wr = (w >> 1) << 5;                                             \
    const int wc = (w & 1) << 6;

// epilogue bounce fence (rule #18)
#define EB_FENCE  asm volatile("s_waitcnt lgkmcnt(0)" ::: "memory");          \
                  __builtin_amdgcn_sched_barrier(0);

// wave-private LDS pipeline: ISS(kb, dst) issues exactly 6 gll16; CMP(src)
// does 6 ds_read_b128 + 8 MFMA. Counted per-wave vmcnt; zero barriers.
#define PIPEW(NT, ISS, CMP)                                                   \
    ISS(0, wb);                                                               \
    ISS(1, wb + 6144);                                                        \
    _Pragma("unroll")                                                         \
    for (int kb = 0; kb < (NT); ++kb) {                                       \
        char* cur = wb + (kb & 1) * 6144;                                     \
        if (kb + 1 < (NT)) { asm volatile("s_waitcnt vmcnt(6)" ::: "memory"); } \
        else               { asm volatile("s_waitcnt vmcnt(0)" ::: "memory"); } \
        __builtin_amdgcn_sched_barrier(0);                                    \
        CMP(cur);                                                             \
        asm volatile("s_waitcnt lgkmcnt(0)" ::: "memory");                    \
        __builtin_amdgcn_sched_barrier(0);                                    \
        if (kb + 2 < (NT)) ISS(kb + 2, cur);                                  \
    }

// ============================ preconversion ==================================
__global__ __launch_bounds__(256) void k_pre_hf(const float* __restrict__ x,
                                                const float* __restrict__ h0,
                                                u16* __restrict__ ws) {
    const int q    = blockIdx.x * 256 + threadIdx.x;
    const int fi   = q >> 6, lane = q & 63;
    const int rb   = fi >> 5, kb = fi & 31;
    const int row  = rb * 16 + (lane & 15);
    const int k8   = (lane >> 4) << 3;
    const float* src;
    if (kb < 16)      src = h0 + (size_t)row * HD + kb * 32 + k8;
    else if (kb < 24) src = h0 + (size_t)row * HD + 512 + (kb - 16) * 32 + k8;
    else if (kb < 28) src = h0 + (size_t)row * HD + 1152 + (kb - 24) * 32 + k8;
    else              src = x  + (size_t)row * 128 + (kb - 28) * 32 + k8;
    float4 u0 = *(const float4*)(src + 0);
    float4 u1 = *(const float4*)(src + 4);
    const float ff[8] = {u0.x, u0.y, u0.z, u0.w, u1.x, u1.y, u1.z, u1.w};
    s16x8 v;
#pragma unroll
    for (int j = 0; j < 8; ++j) v[j] = (short)f2bf(ff[j]);
    *(s16x8*)(ws + ((size_t)fi << 9) + lane * 8) = v;
}

__global__ __launch_bounds__(256) void k_pre_wf(const float* __restrict__ cw,
                                                const float* __restrict__ cwh,
                                                const float* __restrict__ cow,
                                                const float* __restrict__ gwi,
                                                const float* __restrict__ gwh,
                                                u16* __restrict__ dst) {
    const int q  = blockIdx.x * 256 + threadIdx.x;
    const int fi = q >> 6, lane = q & 63;
    const int r15 = lane & 15, k8 = (lane >> 4) << 3;
    const float* src; int K, cb, kb;
    if (fi < 384)       { src = cw;  K = 256; cb = fi >> 3;          kb = fi & 7; }
    else if (fi < 768)  { src = cwh; K = 256; cb = (fi - 384) >> 3;  kb = (fi - 384) & 7; }
    else if (fi < 896)  { src = cow; K = 256; cb = (fi - 768) >> 3;  kb = (fi - 768) & 7; }
    else if (fi < 1280) { src = gwi; K = 128; cb = (fi - 896) >> 2;  kb = (fi - 896) & 3; }
    else                { src = gwh; K = 512; cb = (fi - 1280) >> 4; kb = (fi - 1280) & 15; }
    const float* p = src + (size_t)(cb * 16 + r15) * K + kb * 32 + k8;
    float4 u0 = *(const float4*)(p + 0);
    float4 u1 = *(const float4*)(p + 4);
    const float ff[8] = {u0.x, u0.y, u0.z, u0.w, u1.x, u1.y, u1.z, u1.w};
    s16x8 v;
#pragma unroll
    for (int j = 0; j < 8; ++j) v[j] = (short)f2bf(ff[j]);
    *(s16x8*)(dst + ((size_t)fi << 9) + lane * 8) = v;
}

__global__ __launch_bounds__(256) void k_pre_fw(const float* __restrict__ fw,
                                                u16* __restrict__ dst) {
    const int col = blockIdx.x * 256 + threadIdx.x;
    float s = 0.f;
    for (int r = 0; r < 128; ++r) {
        float a = fw[r * 512 + col];
        s = fmaf(a, a, s);
    }
    const float inv = 1.0f / fmaxf(sqrtf(s), 1e-12f);
    for (int r = 0; r < 128; ++r)
        dst[r * 512 + col] = f2bf(fw[r * 512 + col] * inv);
}

// =============================== con_rz ======================================
// grid 1024: gate = lb&1 (0=z,1=r), colblk = (lb>>1)&1, rp = lb>>2
__global__ __launch_bounds__(256, 3) void k_con_rz(
    const u16* __restrict__ ws, const float* __restrict__ h0,
    const float* __restrict__ bih, const float* __restrict__ bhh,
    float* out) {
    __shared__ char PL[49152];
    const int lb   = xswz();
    const int gate = lb & 1;
    const int col0 = ((lb >> 1) & 1) * 128;
    const int row0 = (lb >> 2) * 64;
    GIDX
    char* wb = PL + w * 12288;
    const int rb0 = (row0 + wr) >> 4;
    const int cbw = (gate ? 16 : 0) + ((col0 + wc) >> 4);
    const u16* wcw  = ws + OFF_CW;
    const u16* wcwh = ws + OFF_CWH;
    f32x4 acc[2][4] = {};
    auto ISS = [&](int kb, char* dst) {
        const int pkb = (kb < 4) ? (28 + kb) : (kb < 8) ? (20 + kb) : (8 + kb);
        gll16(PF(ws, rb0, pkb) + l * 8, dst);
        gll16(PF(ws, rb0 + 1, pkb) + l * 8, dst + 1024);
#pragma unroll
        for (int j = 0; j < 4; ++j) {
            const u16* bs = (kb < 8) ? wcw  + (((cbw + j) * 8 + kb) << 9)
                                     : wcwh + (((cbw + j) * 8 + kb - 8) << 9);
            gll16(bs + l * 8, dst + 2048 + j * 1024);
        }
    };
    auto CMP = [&](const char* s) {
        bf16x8 a0 = *(const bf16x8*)(s + l * 16);
        bf16x8 a1 = *(const bf16x8*)(s + 1024 + l * 16);
#pragma unroll
        for (int j = 0; j < 4; ++j) {
            bf16x8 b = *(const bf16x8*)(s + 2048 + j * 1024 + l * 16);
            acc[0][j] = MFMA(a0, b, acc[0][j]);
            acc[1][j] = MFMA(a1, b, acc[1][j]);
        }
    };
    PIPEW(16, ISS, CMP)
    if (gate) {                                     // r -> rhC frags
        char* eb = wb;
#pragma unroll
        for (int f = 0; f < 2; ++f)
#pragma unroll
            for (int j = 0; j < 4; ++j)
#pragma unroll
                for (int t = 0; t < 4; ++t) {
                    int rl  = f * 16 + (l >> 4) * 4 + t;
                    int row = row0 + wr + rl;
                    int c   = col0 + wc + j * 16 + (l & 15);
                    float rv = sigm(acc[f][j][t] + bih[256 + c] + bhh[256 + c]);
                    float hv = h0[(size_t)row * HD + 512 + c];
                    ldsw16(eb, rl, j * 16 + (l & 15), f2bf(rv * hv));
                }
        EB_FENCE
#pragma unroll
        for (int rf = 0; rf < 2; ++rf)
#pragma unroll
            for (int kb2 = 0; kb2 < 2; ++kb2) {
                bf16x8 v = ldfrag(eb, rf * 16 + (l & 15), kb2, l >> 4);
                const int kbg = ((col0 + wc) >> 5) + kb2;
                *(bf16x8*)((char*)out + (size_t)((rb0 + rf) * 16 + kbg) * 5120
                           + 1024 + l * 16) = v;
            }
    } else {                                        // z -> sigm f32 at out[0:256)
#pragma unroll
        for (int f = 0; f < 2; ++f)
#pragma unroll
            for (int j = 0; j < 4; ++j)
#pragma unroll
                for (int t = 0; t < 4; ++t) {
                    int row = row0 + wr + f * 16 + (l >> 4) * 4 + t;
                    int c   = col0 + wc + j * 16 + (l & 15);
                    out[(size_t)row * HD + c] = sigm(acc[f][j][t] + bih[c] + bhh[c]);
                }
    }
}

// =============================== con_n =======================================
__global__ __launch_bounds__(256, 3) void k_con_n(
    const u16* __restrict__ ws, const float* __restrict__ h0,
    const float* __restrict__ bih, const float* __restrict__ bhh,
    float* out) {
    __shared__ char PL[49152];
    const int lb   = xswz();
    const int col0 = (lb & 1) * 128;
    const int row0 = (lb >> 1) * 64;
    GIDX
    char* wb = PL + w * 12288;
    const int rb0 = (row0 + wr) >> 4;
    const int cbw = 32 + ((col0 + wc) >> 4);
    const u16* wcw  = ws + OFF_CW;
    const u16* wcwh = ws + OFF_CWH;
    const char* outb = (const char*)out;
    f32x4 acc[2][4] = {};
    auto ISS = [&](int kb, char* dst) {
        if (kb < 8) {
            const int pkb = (kb < 4) ? (28 + kb) : (20 + kb);
            gll16(PF(ws, rb0, pkb) + l * 8, dst);
            gll16(PF(ws, rb0 + 1, pkb) + l * 8, dst + 1024);
        } else {
            gll16(outb + (size_t)(rb0 * 16 + kb - 8) * 5120 + 1024 + l * 16, dst);
            gll16(outb + (size_t)((rb0 + 1) * 16 + kb - 8) * 5120 + 1024 + l * 16, dst + 1024);
        }
#pragma unroll
        for (int j = 0; j < 4; ++j) {
            const u16* bs = (kb < 8) ? wcw  + (((cbw + j) * 8 + kb) << 9)
                                     : wcwh + (((cbw + j) * 8 + kb - 8) << 9);
            gll16(bs + l * 8, dst + 2048 + j * 1024);
        }
    };
    auto CMP = [&](const char* s) {
        bf16x8 a0 = *(const bf16x8*)(s + l * 16);
        bf16x8 a1 = *(const bf16x8*)(s + 1024 + l * 16);
#pragma unroll
        for (int j = 0; j < 4; ++j) {
            bf16x8 b = *(const bf16x8*)(s + 2048 + j * 1024 + l * 16);
            acc[0][j] = MFMA(a0, b, acc[0][j]);
            acc[1][j] = MFMA(a1, b, acc[1][j]);
        }
    };
    PIPEW(16, ISS, CMP)
    char* eb = wb;
#pragma unroll
    for (int f = 0; f < 2; ++f)
#pragma unroll
        for (int j = 0; j < 4; ++j)
#pragma unroll
            for (int t = 0; t < 4; ++t) {
                int rl  = f * 16 + (l >> 4) * 4 + t;
                int row = row0 + wr + rl;
                int c   = col0 + wc + j * 16 + (l & 15);
                float zv = out[(size_t)row * HD + c];                 // zC
                float nv = tanhf(acc[f][j][t] + bih[512 + c] + bhh[512 + c]);
                float hv = h0[(size_t)row * HD + 512 + c];
                float hp = zv * hv + (1.0f - zv) * nv;
                hp = fminf(fmaxf(hp, -CLIPV), CLIPV);
                out[(size_t)row * HD + 512 + c] = hp;                 // con_state
                ldsw16(eb, rl, j * 16 + (l & 15), f2bf(hp));
            }
    EB_FENCE
#pragma unroll
    for (int rf = 0; rf < 2; ++rf)
#pragma unroll
        for (int kb2 = 0; kb2 < 2; ++kb2) {
            bf16x8 v = ldfrag(eb, rf * 16 + (l & 15), kb2, l >> 4);
            const int kbg = ((col0 + wc) >> 5) + kb2;
            *(bf16x8*)((char*)out + (size_t)((rb0 + rf) * 16 + 8 + kbg) * 5120
                       + 1024 + l * 16) = v;                          // cs
        }
}

// ================================= co ========================================
__global__ __launch_bounds__(256, 3) void k_co(
    const u16* __restrict__ ws, const float* __restrict__ cb_,
    float* out) {
    __shared__ char PL[49152];
    const int lb = xswz();
    const int col0 = (lb & 1) * 128;
    const int row0 = (lb >> 1) * 64;
    GIDX
    char* wb = PL + w * 12288;
    const int rb0 = (row0 + wr) >> 4;
    const int cbw = (col0 + wc) >> 4;
    const u16* wcow = ws + OFF_COW;
    const char* outb = (const char*)out;
    f32x4 acc[2][4] = {};
    auto ISS = [&](int kb, char* dst) {
        gll16(outb + (size_t)(rb0 * 16 + 8 + kb) * 5120 + 1024 + l * 16, dst);
        gll16(outb + (size_t)((rb0 + 1) * 16 + 8 + kb) * 5120 + 1024 + l * 16, dst + 1024);
#pragma unroll
        for (int j = 0; j < 4; ++j)
            gll16(wcow + (((cbw + j) * 8 + kb) << 9) + l * 8, dst + 2048 + j * 1024);
    };
    auto CMP = [&](const char* s) {
        bf16x8 a0 = *(const bf16x8*)(s + l * 16);
        bf16x8 a1 = *(const bf16x8*)(s + 1024 + l * 16);
#pragma unroll
        for (int j = 0; j < 4; ++j) {
            bf16x8 b = *(const bf16x8*)(s + 2048 + j * 1024 + l * 16);
            acc[0][j] = MFMA(a0, b, acc[0][j]);
            acc[1][j] = MFMA(a1, b, acc[1][j]);
        }
    };
    PIPEW(8, ISS, CMP)
    char* eb = wb;
#pragma unroll
    for (int f = 0; f < 2; ++f)
#pragma unroll
        for (int j = 0; j < 4; ++j)
#pragma unroll
            for (int t = 0; t < 4; ++t) {
                int rl  = f * 16 + (l >> 4) * 4 + t;
                int row = row0 + wr + rl;
                int c   = col0 + wc + j * 16 + (l & 15);
                float v = acc[f][j][t] + cb_[c];
                if (col0 == 0) {                    // co_mean half
                    out[(size_t)row * HD + 1024 + c] = v;             // gen_input
                    out[(size_t)row * HD + 768 + c]  = v;             // mean
                    ldsw16(eb, rl, j * 16 + (l & 15), f2bf(v));
                } else {
                    out[(size_t)row * HD + 896 + (c - 128)] = v;      // logstd
                }
            }
    if (col0 == 0) {
        EB_FENCE
#pragma unroll
        for (int rf = 0; rf < 2; ++rf)
#pragma unroll
            for (int kb2 = 0; kb2 < 2; ++kb2) {
                bf16x8 v = ldfrag(eb, rf * 16 + (l & 15), kb2, l >> 4);
                const int kbg = (wc >> 5) + kb2;
                char* base = (char*)out + (size_t)((rb0 + rf) * 16 + kbg * 2) * 5120 + 4608;
                *(bf16x8*)(base + (l >> 5) * 5120 + (l & 31) * 16) = v;  // gi
            }
    }
}

// =============================== gen_rz ======================================
// grid 2048: gate = lb&1 (0=z,1=r), colblk = (lb>>1)&3, rp = lb>>3
__global__ __launch_bounds__(256, 3) void k_gen_rz(
    u16* __restrict__ ws, const float* __restrict__ h0,
    const float* __restrict__ bih, const float* __restrict__ bhh,
    float* out) {
    __shared__ char PL[49152];
    const int lb   = xswz();
    const int gate = lb & 1;
    const int col0 = ((lb >> 1) & 3) * 128;
    const int row0 = (lb >> 3) * 64;
    GIDX
    char* wb = PL + w * 12288;
    const int rb0 = (row0 + wr) >> 4;
    const int cbw = (gate ? 32 : 0) + ((col0 + wc) >> 4);
    const u16* wgwi = ws + OFF_GWI;
    const u16* wgwh = ws + OFF_GWH;
    const char* outb = (const char*)out;
    f32x4 acc[2][4] = {};
    auto ISS = [&](int kb, char* dst) {
        if (kb < 4) {
            gll16(outb + (size_t)(rb0 * 16 + kb * 2) * 5120 + 4608
                  + (l >> 5) * 5120 + (l & 31) * 16, dst);
            gll16(outb + (size_t)((rb0 + 1) * 16 + kb * 2) * 5120 + 4608
                  + (l >> 5) * 5120 + (l & 31) * 16, dst + 1024);
        } else {
            gll16(PF(ws, rb0, kb - 4) + l * 8, dst);
            gll16(PF(ws, rb0 + 1, kb - 4) + l * 8, dst + 1024);
        }
#pragma unroll
        for (int j = 0; j < 4; ++j) {
            const u16* bs = (kb < 4) ? wgwi + (((cbw + j) * 4 + kb) << 9)
                                     : wgwh + (((cbw + j) * 16 + kb - 4) << 9);
            gll16(bs + l * 8, dst + 2048 + j * 1024);
        }
    };
    auto CMP = [&](const char* s) {
        bf16x8 a0 = *(const bf16x8*)(s + l * 16);
        bf16x8 a1 = *(const bf16x8*)(s + 1024 + l * 16);
#pragma unroll
        for (int j = 0; j < 4; ++j) {
            bf16x8 b = *(const bf16x8*)(s + 2048 + j * 1024 + l * 16);
            acc[0][j] = MFMA(a0, b, acc[0][j]);
            acc[1][j] = MFMA(a1, b, acc[1][j]);
        }
    };
    PIPEW(20, ISS, CMP)
    if (gate) {                                     // r -> rhG frags (panel)
        char* eb = wb;
#pragma unroll
        for (int f = 0; f < 2; ++f)
#pragma unroll
            for (int j = 0; j < 4; ++j)
#pragma unroll
                for (int t = 0; t < 4; ++t) {
                    int rl  = f * 16 + (l >> 4) * 4 + t;
                    int row = row0 + wr + rl;
                    int c   = col0 + wc + j * 16 + (l & 15);
                    float rv = sigm(acc[f][j][t] + bih[512 + c] + bhh[512 + c]);
                    float hv = h0[(size_t)row * HD + c];
                    ldsw16(eb, rl, j * 16 + (l & 15), f2bf(rv * hv));
                }
        EB_FENCE
#pragma unroll
        for (int rf = 0; rf < 2; ++rf)
#pragma unroll
            for (int kb2 = 0; kb2 < 2; ++kb2) {
                bf16x8 v = ldfrag(eb, rf * 16 + (l & 15), kb2, l >> 4);
                const int kbg = ((col0 + wc) >> 5) + kb2;       // 0..15
                *(bf16x8*)((u16*)PF(ws, rb0 + rf, 16 + kbg) + l * 8) = v;
            }
    } else {                                        // z -> sigm f32 at out[0:512)
#pragma unroll
        for (int f = 0; f < 2; ++f)
#pragma unroll
            for (int j = 0; j < 4; ++j)
#pragma unroll
                for (int t = 0; t < 4; ++t) {
                    int row = row0 + wr + f * 16 + (l >> 4) * 4 + t;
                    int c   = col0 + wc + j * 16 + (l & 15);
                    out[(size_t)row * HD + c] = sigm(acc[f][j][t] + bih[c] + bhh[c]);
                }
    }
}

// =============================== gen_n =======================================
__global__ __launch_bounds__(256, 3) void k_gen_n(
    const u16* __restrict__ ws, const float* __restrict__ h0,
    const float* __restrict__ bih, const float* __restrict__ bhh,
    float* out) {
    __shared__ char PL[49152];
    const int lb   = xswz();
    const int col0 = (lb & 3) * 128;
    const int row0 = (lb >> 2) * 64;
    GIDX
    char* wb = PL + w * 12288;
    const int rb0 = (row0 + wr) >> 4;
    const int cbw = 64 + ((col0 + wc) >> 4);
    const u16* wgwi = ws + OFF_GWI;
    const u16* wgwh = ws + OFF_GWH;
    const char* outb = (const char*)out;
    f32x4 acc[2][4] = {};
    auto ISS = [&](int kb, char* dst) {
        if (kb < 4) {
            gll16(outb + (size_t)(rb0 * 16 + kb * 2) * 5120 + 4608
                  + (l >> 5) * 5120 + (l & 31) * 16, dst);
            gll16(outb + (size_t)((rb0 + 1) * 16 + kb * 2) * 5120 + 4608
                  + (l >> 5) * 5120 + (l & 31) * 16, dst + 1024);
        } else {
            gll16(PF(ws, rb0, 16 + kb - 4) + l * 8, dst);          // rhG
            gll16(PF(ws, rb0 + 1, 16 + kb - 4) + l * 8, dst + 1024);
        }
#pragma unroll
        for (int j = 0; j < 4; ++j) {
            const u16* bs = (kb < 4) ? wgwi + (((cbw + j) * 4 + kb) << 9)
                                     : wgwh + (((cbw + j) * 16 + kb - 4) << 9);
            gll16(bs + l * 8, dst + 2048 + j * 1024);
        }
    };
    auto CMP = [&](const char* s) {
        bf16x8 a0 = *(const bf16x8*)(s + l * 16);
        bf16x8 a1 = *(const bf16x8*)(s + 1024 + l * 16);
#pragma unroll
        for (int j = 0; j < 4; ++j) {
            bf16x8 b = *(const bf16x8*)(s + 2048 + j * 1024 + l * 16);
            acc[0][j] = MFMA(a0, b, acc[0][j]);
            acc[1][j] = MFMA(a1, b, acc[1][j]);
        }
    };
    PIPEW(20, ISS, CMP)
#pragma unroll
    for (int f = 0; f < 2; ++f)
#pragma unroll
        for (int j = 0; j < 4; ++j)
#pragma unroll
            for (int t = 0; t < 4; ++t) {
                int row = row0 + wr + f * 16 + (l >> 4) * 4 + t;
                int c   = col0 + wc + j * 16 + (l & 15);
                float zv = out[(size_t)row * HD + c];             // zG
                float nv = tanhf(acc[f][j][t] + bih[1024 + c] + bhh[1024 + c]);
                float hv = h0[(size_t)row * HD + c];
                float hp = zv * hv + (1.0f - zv) * nv;
                out[(size_t)row * HD + c] = fminf(fmaxf(hp, -CLIPV), CLIPV);
            }
}

// ===================== LDS gemm1 machinery (fac + fallback) =================
struct KSrc {
    const void* p[5];
    int ld[5];
    int kind[5];
    const float* scale;
};

template <int R>
__device__ __forceinline__ void stage_issue(char* tile, const KSrc& S, int rbase,
                                            int k0, int sIdx, float* regs) {
    const int tid = threadIdx.x;
    if (S.kind[sIdx]) {
        const char* base = (const char*)S.p[sIdx];
        const int w = tid >> 6;
        const size_t ld = (size_t)S.ld[sIdx];
#pragma unroll
        for (int e = 0; e < R / 32; ++e) {
            const int q = e * 256 + tid;
            const int r = q >> 3;
            const int b = ((q & 7) << 4) ^ ((r & 7) << 4);
            gll16(base + ((size_t)(rbase + r) * ld + k0) * 2 + b, tile + e * 4096 + w * 1024);
        }
    } else {
        const float* base = (const float*)S.p[sIdx];
        const size_t ld = (size_t)S.ld[sIdx];
#pragma unroll
        for (int e = 0; e < R / 64; ++e) {
            const int q = e * 256 + tid;
            const int r = q >> 2;
            const int kloc = (q & 3) << 4;
            const float* pp = base + (size_t)(rbase + r) * ld + k0 + kloc;
            float* d = regs + e * 16;
            *(float4*)(d + 0)  = *(const float4*)(pp + 0);
            *(float4*)(d + 4)  = *(const float4*)(pp + 4);
            *(float4*)(d + 8)  = *(const float4*)(pp + 8);
            *(float4*)(d + 12) = *(const float4*)(pp + 12);
        }
    }
}

template <int R>
__device__ __forceinline__ void stage_write(char* tile, const KSrc& S, int rbase,
                                            int k0, int sIdx, float* regs) {
    if (S.kind[sIdx]) return;
    const int tid = threadIdx.x;
#pragma unroll
    for (int e = 0; e < R / 64; ++e) {
        const int q = e * 256 + tid;
        const int r = q >> 2;
        float* ff = regs + e * 16;
        if (S.scale) {
            const int kabs = k0 + ((q & 3) << 4);
#pragma unroll
            for (int j = 0; j < 16; ++j) ff[j] *= S.scale[kabs + j];
        }
        s16x8 v0, v1;
#pragma unroll
        for (int j = 0; j < 8; ++j) {
            v0[j] = (short)f2bf(ff[j]);
            v1[j] = (short)f2bf(ff[j + 8]);
        }
        const int swz = (r & 7) << 4;
        *(s16x8*)(tile + r * 128 + ((((q & 3) << 5) + 0)  ^ swz)) = v0;
        *(s16x8*)(tile + r * 128 + ((((q & 3) << 5) + 16) ^ swz)) = v1;
    }
}

__device__ __forceinline__ void cmp64_4w(f32x4 (&acc)[2][4], const char* At, const char* Wt) {
    const int l = threadIdx.x & 63, w = threadIdx.x >> 6;
    const int wr = (w >> 1) << 5, wc = (w & 1) << 6;
    const int g = l >> 4, r15 = l & 15;
#pragma unroll
    for (int ks = 0; ks < 2; ++ks) {
        bf16x8 a[2], b[4];
#pragma unroll
        for (int f = 0; f < 2; ++f) a[f] = ldfrag(At, wr + f * 16 + r15, ks, g);
#pragma unroll
        for (int f = 0; f < 4; ++f) b[f] = ldfrag(Wt, wc + f * 16 + r15, ks, g);
#pragma unroll
        for (int i = 0; i < 2; ++i)
#pragma unroll
            for (int j = 0; j < 4; ++j)
                acc[i][j] = MFMA(a[i], b[j], acc[i][j]);
    }
}

template <int NT>
__device__ __forceinline__ void gemm1(f32x4 (&acc)[2][4], char* At, char* Wt,
                                      const KSrc& A, const KSrc& W,
                                      int row0, int col0) {
    float ra[16], rw[32];
#pragma unroll
    for (int kt = 0; kt < NT; ++kt) {
        const int s = kt >> 1;
        __syncthreads();
        stage_issue<64> (At, A, row0, kt * 64, s, ra);
        stage_issue<128>(Wt, W, col0, kt * 64, s, rw);
        stage_write<64> (At, A, row0, kt * 64, s, ra);
        stage_write<128>(Wt, W, col0, kt * 64, s, rw);
        __syncthreads();
        cmp64_4w(acc, At, Wt);
    }
}

#define FB_SHARED __shared__ alignas(16) char At[8192], Wt[16384];
#define FB_IDX                                                              \
    const int l  = threadIdx.x & 63;                                        \
    const int w  = threadIdx.x >> 6;                                        \
    const int wr = (w >> 1) << 5;                                           \
    const int wc = (w & 1) << 6;

// ------------------------------ fac (PRE) ------------------------------------
__global__ __launch_bounds__(256) void k_facp(
    const u16* __restrict__ ws, float* __restrict__ out) {
    FB_SHARED
    const int row0 = xswz() * 64;
    KSrc A = {{out, out, out, out, nullptr},
              {HD, HD, HD, HD, 0}, {0, 0, 0, 0, 0}, nullptr};
    KSrc W = {{ws + OFF_FW, ws + OFF_FW, ws + OFF_FW, ws + OFF_FW, nullptr},
              {512, 512, 512, 512, 0}, {1, 1, 1, 1, 0}, nullptr};
    f32x4 acc[2][4] = {};
    gemm1<8>(acc, At, Wt, A, W, row0, 0);
    FB_IDX
#pragma unroll
    for (int i = 0; i < 2; ++i)
#pragma unroll
        for (int j = 0; j < 4; ++j)
#pragma unroll
            for (int t = 0; t < 4; ++t) {
                int row = row0 + wr + i * 16 + (l >> 4) * 4 + t;
                int c   = wc + j * 16 + (l & 15);
                out[(size_t)row * HD + 1152 + c] = acc[i][j][t];
            }
}

// ===================== fallback path (no usable ws) =========================
__global__ __launch_bounds__(256) void f_con_r(
    const float* __restrict__ x, const float* __restrict__ h0,
    const float* __restrict__ wih, const float* __restrict__ bih,
    const float* __restrict__ whh, const float* __restrict__ bhh,
    float* __restrict__ out) {
    FB_SHARED
    const int lb = xswz();
    const int col0 = (lb & 1) * 128;
    const int row0 = (lb >> 1) * 64;
    KSrc A = {{x, h0 + 1024, h0 + 256, h0 + 256, nullptr},
              {128, HD, HD, HD, 0}, {0, 0, 0, 0, 0}, nullptr};
    KSrc W = {{wih + 65536, wih + 65536, whh + 65536 - 256, whh + 65536 - 256, nullptr},
              {256, 256, 256, 256, 0}, {0, 0, 0, 0, 0}, nullptr};
    f32x4 acc[2][4] = {};
    gemm1<8>(acc, At, Wt, A, W, row0, col0);
    FB_IDX
    u16* outs = (u16*)out;
#pragma unroll
    for (int i = 0; i < 2; ++i)
#pragma unroll
        for (int j = 0; j < 4; ++j)
#pragma unroll
            for (int t = 0; t < 4; ++t) {
                int row = row0 + wr + i * 16 + (l >> 4) * 4 + t;
                int c   = col0 + wc + j * 16 + (l & 15);
                float rv = sigm(acc[i][j][t] + bih[256 + c] + bhh[256 + c]);
                float hv = h0[(size_t)row * HD + 512 + c];
                outs[(size_t)row * 2560 + 512 + c] = f2bf(rv * hv);
            }
}

__global__ __launch_bounds__(256) void f_con_zn(
    const float* __restrict__ x, const float* __restrict__ h0,
    const float* __restrict__ wih, const float* __restrict__ bih,
    const float* __restrict__ whh, const float* __restrict__ bhh,
    float* __restrict__ out) {
    FB_SHARED
    const int lb = xswz();
    const int col0 = (lb & 1) * 128;
    const int row0 = (lb >> 1) * 64;
    const u16* outs = (const u16*)out;
    KSrc Az = {{x, h0 + 1024, h0 + 256, h0 + 256, nullptr},
               {128, HD, HD, HD, 0}, {0, 0, 0, 0, 0}, nullptr};
    KSrc Wz = {{wih, wih, whh - 256, whh - 256, nullptr},
               {256, 256, 256, 256, 0}, {0, 0, 0, 0, 0}, nullptr};
    KSrc An = {{x, h0 + 1024, outs + 256, outs + 256, nullptr},
               {128, HD, 2560, 2560, 0}, {0, 0, 1, 1, 0}, nullptr};
    KSrc Wn = {{wih + 512 * 256, wih + 512 * 256,
                whh + 512 * 256 - 256, whh + 512 * 256 - 256, nullptr},
               {256, 256, 256, 256, 0}, {0, 0, 0, 0, 0}, nullptr};
    f32x4 aZ[2][4] = {}, aN[2][4] = {};
    gemm1<8>(aZ, At, Wt, Az, Wz, row0, col0);
    gemm1<8>(aN, At, Wt, An, Wn, row0, col0);
    FB_IDX
#pragma unroll
    for (int i = 0; i < 2; ++i)
#pragma unroll
        for (int j = 0; j < 4; ++j)
#pragma unroll
            for (int t = 0; t < 4; ++t) {
                int row = row0 + wr + i * 16 + (l >> 4) * 4 + t;
                int c   = col0 + wc + j * 16 + (l & 15);
                float zv = sigm(aZ[i][j][t] + bih[c] + bhh[c]);
                float nv = tanhf(aN[i][j][t] + bih[512 + c] + bhh[512 + c]);
                float hv = h0[(size_t)row * HD + 512 + c];
                float hp = zv * hv + (1.0f - zv) * nv;
                out[(size_t)row * HD + 512 + c] = fminf(fmaxf(hp, -CLIPV), CLIPV);
            }
}

__global__ __launch_bounds__(256) void f_co(
    const float* __restrict__ cw, const float* __restrict__ cb,
    float* __restrict__ out) {
    FB_SHARED
    const int lb = xswz();
    const int col0 = (lb & 1) * 128;
    const int row0 = (lb >> 1) * 64;
    KSrc A = {{out + 512, out + 512, nullptr, nullptr, nullptr},
              {HD, HD, 0, 0, 0}, {0, 0, 0, 0, 0}, nullptr};
    KSrc W = {{cw, cw, nullptr, nullptr, nullptr},
              {256, 256, 0, 0, 0}, {0, 0, 0, 0, 0}, nullptr};
    f32x4 acc[2][4] = {};
    gemm1<4>(acc, At, Wt, A, W, row0, col0);
    FB_IDX
    u16* outw = (u16*)out;
#pragma unroll
    for (int i = 0; i < 2; ++i)
#pragma unroll
        for (int j = 0; j < 4; ++j)
#pragma unroll
            for (int t = 0; t < 4; ++t) {
                int row = row0 + wr + i * 16 + (l >> 4) * 4 + t;
                int c   = col0 + wc + j * 16 + (l & 15);
                float v = acc[i][j][t] + cb[c];
                if (c < 128) {
                    out[(size_t)row * HD + 1024 + c]    = v;
                    outw[(size_t)row * 2560 + 2304 + c] = f2bf(v);
                }
            }
}

__global__ __launch_bounds__(256) void f_gen_r(
    const float* __restrict__ h0,
    const float* __restrict__ wih, const float* __restrict__ bih,
    const float* __restrict__ whh, const float* __restrict__ bhh,
    float* __restrict__ out) {
    FB_SHARED
    const int lb = xswz();
    const int col0 = (lb & 3) * 128;
    const int row0 = (lb >> 2) * 64;
    const u16* outs = (const u16*)out;
    KSrc A = {{outs + 2304, h0 - 128, h0 - 128, h0 - 128, h0 - 128},
              {2560, HD, HD, HD, HD}, {1, 0, 0, 0, 0}, nullptr};
    KSrc W = {{wih + 65536, whh + 512 * 512 - 128, whh + 512 * 512 - 128,
               whh + 512 * 512 - 128, whh + 512 * 512 - 128},
              {128, 512, 512, 512, 512}, {0, 0, 0, 0, 0}, nullptr};
    f32x4 acc[2][4] = {};
    gemm1<10>(acc, At, Wt, A, W, row0, col0);
    FB_IDX
    u16* outw = (u16*)out;
#pragma unroll
    for (int i = 0; i < 2; ++i)
#pragma unroll
        for (int j = 0; j < 4; ++j)
#pragma unroll
            for (int t = 0; t < 4; ++t) {
                int row = row0 + wr + i * 16 + (l >> 4) * 4 + t;
                int c   = col0 + wc + j * 16 + (l & 15);
                float rv = sigm(acc[i][j][t] + bih[512 + c] + bhh[512 + c]);
                float hv = h0[(size_t)row * HD + c];
                outw[(size_t)row * 2560 + 1536 + c] = f2bf(rv * hv);
            }
}

__global__ __launch_bounds__(256) void f_gen_zn(
    const float* __restrict__ h0,
    const float* __restrict__ wih, const float* __restrict__ bih,
    const float* __restrict__ whh, const float* __restrict__ bhh,
    float* __restrict__ out) {
    FB_SHARED
    const int lb = xswz();
    const int col0 = (lb & 3) * 128;
    const int row0 = (lb >> 2) * 64;
    const u16* outs = (const u16*)out;
    KSrc Az = {{outs + 2304, h0 - 128, h0 - 128, h0 - 128, h0 - 128},
               {2560, HD, HD, HD, HD}, {1, 0, 0, 0, 0}, nullptr};
    KSrc Wz = {{wih, whh - 128, whh - 128, whh - 128, whh - 128},
               {128, 512, 512, 512, 512}, {0, 0, 0, 0, 0}, nullptr};
    KSrc An = {{outs + 2304, outs + 1408, outs + 1408, outs + 1408, outs + 1408},
               {2560, 2560, 2560, 2560, 2560}, {1, 1, 1, 1, 1}, nullptr};
    KSrc Wn = {{wih + 1024 * 128, whh + 1024 * 512 - 128, whh + 1024 * 512 - 128,
                whh + 1024 * 512 - 128, whh + 1024 * 512 - 128},
               {128, 512, 512, 512, 512}, {0, 0, 0, 0, 0}, nullptr};
    f32x4 aZ[2][4] = {}, aN[2][4] = {};
    gemm1<10>(aZ, At, Wt, Az, Wz, row0, col0);
    gemm1<10>(aN, At, Wt, An, Wn, row0, col0);
    FB_IDX
#pragma unroll
    for (int i = 0; i < 2; ++i)
#pragma unroll
        for (int j = 0; j < 4; ++j)
#pragma unroll
            for (int t = 0; t < 4; ++t) {
                int row = row0 + wr + i * 16 + (l >> 4) * 4 + t;
                int c   = col0 + wc + j * 16 + (l & 15);
                float zv = sigm(aZ[i][j][t] + bih[c] + bhh[c]);
                float nv = tanhf(aN[i][j][t] + bih[1024 + c] + bhh[1024 + c]);
                float hv = h0[(size_t)row * HD + c];
                float hp = zv * hv + (1.0f - zv) * nv;
                out[(size_t)row * HD + c] = fminf(fmaxf(hp, -CLIPV), CLIPV);
            }
}

__global__ __launch_bounds__(256) void f_fac(
    const float* __restrict__ fw, float* __restrict__ out) {
    FB_SHARED
    __shared__ float invn[512];
    const int row0 = xswz() * 64;
    {
        const int t = threadIdx.x;
        float s0 = 0.f, s1 = 0.f;
        for (int r = 0; r < 128; ++r) {
            float a0 = fw[r * 512 + t];
            float a1 = fw[r * 512 + t + 256];
            s0 = fmaf(a0, a0, s0);
            s1 = fmaf(a1, a1, s1);
        }
        invn[t]       = 1.0f / fmaxf(sqrtf(s0), 1e-12f);
        invn[t + 256] = 1.0f / fmaxf(sqrtf(s1), 1e-12f);
        __syncthreads();
    }
    KSrc A = {{out, out, out, out, nullptr},
              {HD, HD, HD, HD, 0}, {0, 0, 0, 0, 0}, nullptr};
    KSrc W = {{fw, fw, fw, fw, nullptr},
              {512, 512, 512, 512, 0}, {0, 0, 0, 0, 0}, invn};
    f32x4 acc[2][4] = {};
    gemm1<8>(acc, At, Wt, A, W, row0, 0);
    FB_IDX
#pragma unroll
    for (int i = 0; i < 2; ++i)
#pragma unroll
        for (int j = 0; j < 4; ++j)
#pragma unroll
            for (int t = 0; t < 4; ++t) {
                int row = row0 + wr + i * 16 + (l >> 4) * 4 + t;
                int c   = wc + j * 16 + (l & 15);
                out[(size_t)row * HD + 1152 + c] = acc[i][j][t];
            }
}

__global__ __launch_bounds__(256) void f_co_fin(
    const float* __restrict__ cw, const float* __restrict__ cb,
    float* __restrict__ out) {
    FB_SHARED
    const int row0 = xswz() * 64;
    KSrc A = {{out + 512, out + 512, nullptr, nullptr, nullptr},
              {HD, HD, 0, 0, 0}, {0, 0, 0, 0, 0}, nullptr};
    KSrc W = {{cw + 128 * 256, cw + 128 * 256, nullptr, nullptr, nullptr},
              {256, 256, 0, 0, 0}, {0, 0, 0, 0, 0}, nullptr};
    f32x4 acc[2][4] = {};
    gemm1<4>(acc, At, Wt, A, W, row0, 0);
    FB_IDX
#pragma unroll
    for (int i = 0; i < 2; ++i)
#pragma unroll
        for (int j = 0; j < 4; ++j)
#pragma unroll
            for (int t = 0; t < 4; ++t) {
                int row = row0 + wr + i * 16 + (l >> 4) * 4 + t;
                int c   = wc + j * 16 + (l & 15);
                out[(size_t)row * HD + 896 + c] = acc[i][j][t] + cb[128 + c];
            }
#pragma unroll
    for (int e = 0; e < 8; ++e) {
        int idx = threadIdx.x + e * 256;
        int r   = idx >> 5;
        int cc  = (idx & 31) << 2;
        *(float4*)&out[(size_t)(row0 + r) * HD + 768 + cc] =
            *(const float4*)&out[(size_t)(row0 + r) * HD + 1024 + cc];
    }
}

// ------------------------------- launch -------------------------------------
extern "C" void kernel_launch(void* const* d_in, const int* in_sizes, int n_in,
                              void* d_out, int out_size, void* d_ws, size_t ws_size,
                              hipStream_t stream) {
    const float* x    = (const float*)d_in[0];
    const float* h0   = (const float*)d_in[1];
    const float* cwih = (const float*)d_in[2];
    const float* cbih = (const float*)d_in[3];
    const float* cwhh = (const float*)d_in[4];
    const float* cbhh = (const float*)d_in[5];
    const float* cow  = (const float*)d_in[6];
    const float* cob  = (const float*)d_in[7];
    const float* gwih = (const float*)d_in[8];
    const float* gbih = (const float*)d_in[9];
    const float* gwhh = (const float*)d_in[10];
    const float* gbhh = (const float*)d_in[11];
    const float* fw   = (const float*)d_in[12];
    float* out = (float*)d_out;
    u16* ws = (u16*)d_ws;

    const bool pre = (ws_size >= (size_t)WS_ELEMS * 2);
    if (pre) {
        k_pre_hf<<<8192, 256, 0, stream>>>(x, h0, ws);
        k_pre_wf<<<704,  256, 0, stream>>>(cwih, cwhh, cow, gwih, gwhh, ws + OFF_CW);
        k_pre_fw<<<2,    256, 0, stream>>>(fw, ws + OFF_FW);
        k_con_rz<<<1024, 256, 0, stream>>>(ws, h0, cbih, cbhh, out);
        k_con_n <<<512,  256, 0, stream>>>(ws, h0, cbih, cbhh, out);
        k_co    <<<512,  256, 0, stream>>>(ws, cob, out);
        k_gen_rz<<<2048, 256, 0, stream>>>(ws, h0, gbih, gbhh, out);
        k_gen_n <<<1024, 256, 0, stream>>>(ws, h0, gbih, gbhh, out);
        k_facp  <<<256,  256, 0, stream>>>(ws, out);
    } else {
        f_con_r <<<512,  256, 0, stream>>>(x, h0, cwih, cbih, cwhh, cbhh, out);
        f_con_zn<<<512,  256, 0, stream>>>(x, h0, cwih, cbih, cwhh, cbhh, out);
        f_co    <<<512,  256, 0, stream>>>(cow, cob, out);
        f_gen_r <<<1024, 256, 0, stream>>>(h0, gwih, gbih, gwhh, gbhh, out);
        f_gen_zn<<<1024, 256, 0, stream>>>(h0, gwih, gbih, gwhh, gbhh, out);
        f_fac   <<<256,  256, 0, stream>>>(fw, out);
        f_co_fin<<<256,  256, 0, stream>>>(cow, cob, out);
    }
}

// Round 15
// 185.360 us; speedup vs baseline: 1.1796x; 1.1796x over previous
//
#include <hip/hip_runtime.h>
#include <math.h>

// DecoderCell (LFADS) on MI355X — round 15: clean revert to round-12 (best
// verified configuration, 186.3us). Round 13 (wave-private LDS pipe) was a
// -33us regression; round 14 (launch_bounds(256,8) + asm-tuple loads) core
// dumped (RA cannot satisfy a 64-VGPR cap with forced asm register tuples).
// This is the fragment-packed register-direct MFMA decomposition with
// inline-asm global_load_dwordx4, counted vmcnt(12/6/0) depth-3 pipeline,
// gate-split grids, and XCD-aware swizzle.
//
// PRE pipeline (9 dispatches):
//   pre_hf / pre_wf / pre_fw -> con_rz -> con_n -> co -> gen_rz -> gen_n -> facp
// Scratch liveness (verified rounds 9-13):
//   zC  : out f32 [0:256)   — con_rz(z) -> con_n; dead before gen_rz(z)
//   rhC : out f32 [256:512) frag rows rb*16+kb(0..7)   — con_rz(r) -> con_n
//   cs  : out f32 [256:512) frag rows rb*16+8+kb(0..7) — con_n -> co
//   gi  : out f32 [1152:1280) frag pieces — co -> gen_rz/gen_n; dead before facp
//   zG  : out f32 [0:512)   — gen_rz(z) -> gen_n (same-element read-then-write)
//   rhG : ws panel kb16..31 — gen_rz(r) -> gen_n

#define HD    1280
#define NROW  16384
#define CLIPV 5.0f

typedef float  f32x4  __attribute__((ext_vector_type(4)));
typedef __bf16 bf16x8 __attribute__((ext_vector_type(8)));
typedef short  s16x8  __attribute__((ext_vector_type(8)));
typedef unsigned short u16;

// ws layout (bf16 elems): frag panel [1024 rb][32 kb][64][8] then frag weights.
// panel kbs: hgen 0-15 | hcon 16-23 | factor 24-27 | x 28-31 (16..31 reused as rhG)
#define OFF_CW   16777216              // con wih  frag (48cb x 8kb)
#define OFF_CWH  (OFF_CW  + 196608)    // con whh  frag (48cb x 8kb)
#define OFF_COW  (OFF_CWH + 196608)    // co  w    frag (16cb x 8kb)
#define OFF_GWI  (OFF_COW + 65536)     // gen wih  frag (96cb x 4kb)
#define OFF_GWH  (OFF_GWI + 196608)    // gen whh  frag (96cb x 16kb)
#define OFF_FW   (OFF_GWH + 786432)    // fac w row-major normalized bf16
#define WS_ELEMS (OFF_FW  + 65536)

__device__ __forceinline__ u16 f2bf(float f) {
    unsigned u = __float_as_uint(f);
    u = u + 0x7fffu + ((u >> 16) & 1u);
    return (u16)(u >> 16);
}
__device__ __forceinline__ float sigm(float v) { return 1.0f / (1.0f + __expf(-v)); }

__device__ __forceinline__ int xswz() {
    const int b   = blockIdx.x;
    const int cpx = gridDim.x >> 3;
    return (b & 7) * cpx + (b >> 3);
}

// ---- forced-register asm fragment loads -------------------------------------
__device__ __forceinline__ bf16x8 gldx4(const void* p) {
    f32x4 r;
    asm volatile("global_load_dwordx4 %0, %1, off" : "=v"(r) : "v"(p));
    return __builtin_bit_cast(bf16x8, r);
}
__device__ __forceinline__ bf16x8 gfrag(const u16* p) {
    return gldx4(p + ((threadIdx.x & 63) << 3));
}
__device__ __forceinline__ bf16x8 gfrag2(const char* base) {   // 2x512B pieces
    const int l = threadIdx.x & 63;
    return gldx4(base + (l >> 5) * 5120 + (l & 31) * 16);
}
__device__ __forceinline__ const u16* PF(const u16* ws, int rb, int kb) {
    return ws + (((size_t)(rb * 32 + kb)) << 9);
}

// ---- swizzled LDS tile (32 rows x 64 cols bf16, row stride 128B) -----------
__device__ __forceinline__ bf16x8 ldfrag(const char* lds, int r, int ks, int g) {
    const char* p = lds + r * 128 + ((((ks << 2) + g) << 4) ^ ((r & 7) << 4));
    return __builtin_bit_cast(bf16x8, *(const s16x8*)p);
}
__device__ __forceinline__ void ldsw16(char* tile, int r, int kloc, u16 v) {
    const int byte = r * 128 + ((((kloc >> 3) << 4) ^ ((r & 7) << 4)) + ((kloc & 7) << 1));
    *(u16*)(tile + byte) = v;
}

#define MFMA(a, b, c) __builtin_amdgcn_mfma_f32_16x16x32_bf16(a, b, c, 0, 0, 0)

#define GIDX                                                                  \
    const int l  = threadIdx.x & 63;                                          \
    const int w  = threadIdx.x >> 6;                                          \
    const int wr = (w >> 1) << 5;                                             \
    const int wc = (w & 1) << 6;

// epilogue bounce fence (rule #18)
#define EB_FENCE  asm volatile("s_waitcnt lgkmcnt(0)" ::: "memory");          \
                  __builtin_amdgcn_sched_barrier(0);

// counted vmcnt waits for the asm-load pipeline (rule #18: fence after)
#define VMW12 { asm volatile("s_waitcnt vmcnt(12)"); __builtin_amdgcn_sched_barrier(0); }
#define VMW6  { asm volatile("s_waitcnt vmcnt(6)");  __builtin_amdgcn_sched_barrier(0); }
#define VMW0  { asm volatile("s_waitcnt vmcnt(0)");  __builtin_amdgcn_sched_barrier(0); }

// depth-3 pipeline: LD = exactly 6 asm loads in every kernel. Outstanding
// before iteration kb's wait: 18 (or 12/6 at tail) -> wait leaves LD(kb) done.
#define PIPE3(NT, LD, FM)                                                     \
    LD(0, A0, B0);                                                            \
    LD(1, A1, B1);                                                            \
    LD(2, A2, B2);                                                            \
    _Pragma("unroll")                                                         \
    for (int kb = 0; kb < (NT); ++kb) {                                       \
        if (kb + 3 < (NT))      VMW12                                         \
        else if (kb + 2 < (NT)) VMW12                                         \
        else if (kb + 1 < (NT)) VMW6                                          \
        else                    VMW0                                          \
        if (kb % 3 == 0)      FM(A0, B0);                                     \
        else if (kb % 3 == 1) FM(A1, B1);                                     \
        else                  FM(A2, B2);                                     \
        __builtin_amdgcn_sched_barrier(0);                                    \
        if (kb + 3 < (NT)) {                                                  \
            if (kb % 3 == 0)      LD(kb + 3, A0, B0);                         \
            else if (kb % 3 == 1) LD(kb + 3, A1, B1);                         \
            else                  LD(kb + 3, A2, B2);                         \
        }                                                                     \
    }

// ============================ preconversion ==================================
__global__ __launch_bounds__(256) void k_pre_hf(const float* __restrict__ x,
                                                const float* __restrict__ h0,
                                                u16* __restrict__ ws) {
    const int q    = blockIdx.x * 256 + threadIdx.x;
    const int fi   = q >> 6, lane = q & 63;
    const int rb   = fi >> 5, kb = fi & 31;
    const int row  = rb * 16 + (lane & 15);
    const int k8   = (lane >> 4) << 3;
    const float* src;
    if (kb < 16)      src = h0 + (size_t)row * HD + kb * 32 + k8;
    else if (kb < 24) src = h0 + (size_t)row * HD + 512 + (kb - 16) * 32 + k8;
    else if (kb < 28) src = h0 + (size_t)row * HD + 1152 + (kb - 24) * 32 + k8;
    else              src = x  + (size_t)row * 128 + (kb - 28) * 32 + k8;
    float4 u0 = *(const float4*)(src + 0);
    float4 u1 = *(const float4*)(src + 4);
    const float ff[8] = {u0.x, u0.y, u0.z, u0.w, u1.x, u1.y, u1.z, u1.w};
    s16x8 v;
#pragma unroll
    for (int j = 0; j < 8; ++j) v[j] = (short)f2bf(ff[j]);
    *(s16x8*)(ws + ((size_t)fi << 9) + lane * 8) = v;
}

__global__ __launch_bounds__(256) void k_pre_wf(const float* __restrict__ cw,
                                                const float* __restrict__ cwh,
                                                const float* __restrict__ cow,
                                                const float* __restrict__ gwi,
                                                const float* __restrict__ gwh,
                                                u16* __restrict__ dst) {
    const int q  = blockIdx.x * 256 + threadIdx.x;
    const int fi = q >> 6, lane = q & 63;
    const int r15 = lane & 15, k8 = (lane >> 4) << 3;
    const float* src; int K, cb, kb;
    if (fi < 384)       { src = cw;  K = 256; cb = fi >> 3;          kb = fi & 7; }
    else if (fi < 768)  { src = cwh; K = 256; cb = (fi - 384) >> 3;  kb = (fi - 384) & 7; }
    else if (fi < 896)  { src = cow; K = 256; cb = (fi - 768) >> 3;  kb = (fi - 768) & 7; }
    else if (fi < 1280) { src = gwi; K = 128; cb = (fi - 896) >> 2;  kb = (fi - 896) & 3; }
    else                { src = gwh; K = 512; cb = (fi - 1280) >> 4; kb = (fi - 1280) & 15; }
    const float* p = src + (size_t)(cb * 16 + r15) * K + kb * 32 + k8;
    float4 u0 = *(const float4*)(p + 0);
    float4 u1 = *(const float4*)(p + 4);
    const float ff[8] = {u0.x, u0.y, u0.z, u0.w, u1.x, u1.y, u1.z, u1.w};
    s16x8 v;
#pragma unroll
    for (int j = 0; j < 8; ++j) v[j] = (short)f2bf(ff[j]);
    *(s16x8*)(dst + ((size_t)fi << 9) + lane * 8) = v;
}

__global__ __launch_bounds__(256) void k_pre_fw(const float* __restrict__ fw,
                                                u16* __restrict__ dst) {
    const int col = blockIdx.x * 256 + threadIdx.x;
    float s = 0.f;
    for (int r = 0; r < 128; ++r) {
        float a = fw[r * 512 + col];
        s = fmaf(a, a, s);
    }
    const float inv = 1.0f / fmaxf(sqrtf(s), 1e-12f);
    for (int r = 0; r < 128; ++r)
        dst[r * 512 + col] = f2bf(fw[r * 512 + col] * inv);
}

// =============================== con_rz ======================================
// grid 1024: gate = lb&1 (0=z,1=r), colblk = (lb>>1)&1, rp = lb>>2
__global__ __launch_bounds__(256, 4) void k_con_rz(
    const u16* __restrict__ ws, const float* __restrict__ h0,
    const float* __restrict__ bih, const float* __restrict__ bhh,
    float* out) {
    __shared__ char EB[4][4096];
    const int lb   = xswz();
    const int gate = lb & 1;
    const int col0 = ((lb >> 1) & 1) * 128;
    const int row0 = (lb >> 2) * 64;
    GIDX
    const int rb0 = (row0 + wr) >> 4;
    const int cbw = (gate ? 16 : 0) + ((col0 + wc) >> 4);
    const u16* wcw  = ws + OFF_CW;
    const u16* wcwh = ws + OFF_CWH;
    f32x4 acc[2][4] = {};
    bf16x8 A0[2], B0[4], A1[2], B1[4], A2[2], B2[4];
    auto LD = [&](int kb, bf16x8 (&A)[2], bf16x8 (&B)[4]) {
        const int pkb = (kb < 4) ? (28 + kb) : (kb < 8) ? (20 + kb) : (8 + kb);
        A[0] = gfrag(PF(ws, rb0, pkb));
        A[1] = gfrag(PF(ws, rb0 + 1, pkb));
#pragma unroll
        for (int j = 0; j < 4; ++j)
            B[j] = (kb < 8) ? gfrag(wcw  + (((cbw + j) * 8 + kb) << 9))
                            : gfrag(wcwh + (((cbw + j) * 8 + kb - 8) << 9));
    };
    auto FM = [&](bf16x8 (&A)[2], bf16x8 (&B)[4]) {
#pragma unroll
        for (int j = 0; j < 4; ++j) {
            acc[0][j] = MFMA(A[0], B[j], acc[0][j]);
            acc[1][j] = MFMA(A[1], B[j], acc[1][j]);
        }
    };
    PIPE3(16, LD, FM)
    if (gate) {                                     // r -> rhC frags
        char* eb = EB[w];
#pragma unroll
        for (int f = 0; f < 2; ++f)
#pragma unroll
            for (int j = 0; j < 4; ++j)
#pragma unroll
                for (int t = 0; t < 4; ++t) {
                    int rl  = f * 16 + (l >> 4) * 4 + t;
                    int row = row0 + wr + rl;
                    int c   = col0 + wc + j * 16 + (l & 15);
                    float rv = sigm(acc[f][j][t] + bih[256 + c] + bhh[256 + c]);
                    float hv = h0[(size_t)row * HD + 512 + c];
                    ldsw16(eb, rl, j * 16 + (l & 15), f2bf(rv * hv));
                }
        EB_FENCE
#pragma unroll
        for (int rf = 0; rf < 2; ++rf)
#pragma unroll
            for (int kb2 = 0; kb2 < 2; ++kb2) {
                bf16x8 v = ldfrag(eb, rf * 16 + (l & 15), kb2, l >> 4);
                const int kbg = ((col0 + wc) >> 5) + kb2;
                *(bf16x8*)((char*)out + (size_t)((rb0 + rf) * 16 + kbg) * 5120
                           + 1024 + l * 16) = v;
            }
    } else {                                        // z -> sigm f32 at out[0:256)
#pragma unroll
        for (int f = 0; f < 2; ++f)
#pragma unroll
            for (int j = 0; j < 4; ++j)
#pragma unroll
                for (int t = 0; t < 4; ++t) {
                    int row = row0 + wr + f * 16 + (l >> 4) * 4 + t;
                    int c   = col0 + wc + j * 16 + (l & 15);
                    out[(size_t)row * HD + c] = sigm(acc[f][j][t] + bih[c] + bhh[c]);
                }
    }
}

// =============================== con_n =======================================
__global__ __launch_bounds__(256, 4) void k_con_n(
    const u16* __restrict__ ws, const float* __restrict__ h0,
    const float* __restrict__ bih, const float* __restrict__ bhh,
    float* out) {
    __shared__ char EB[4][4096];
    const int lb   = xswz();
    const int col0 = (lb & 1) * 128;
    const int row0 = (lb >> 1) * 64;
    GIDX
    const int rb0 = (row0 + wr) >> 4;
    const int cbw = 32 + ((col0 + wc) >> 4);
    const u16* wcw  = ws + OFF_CW;
    const u16* wcwh = ws + OFF_CWH;
    const char* outb = (const char*)out;
    f32x4 acc[2][4] = {};
    bf16x8 A0[2], B0[4], A1[2], B1[4], A2[2], B2[4];
    auto LD = [&](int kb, bf16x8 (&A)[2], bf16x8 (&B)[4]) {
        if (kb < 8) {
            const int pkb = (kb < 4) ? (28 + kb) : (20 + kb);
            A[0] = gfrag(PF(ws, rb0, pkb));
            A[1] = gfrag(PF(ws, rb0 + 1, pkb));
        } else {
            A[0] = gldx4(outb + (size_t)(rb0 * 16 + kb - 8) * 5120 + 1024 + l * 16);
            A[1] = gldx4(outb + (size_t)((rb0 + 1) * 16 + kb - 8) * 5120 + 1024 + l * 16);
        }
#pragma unroll
        for (int j = 0; j < 4; ++j)
            B[j] = (kb < 8) ? gfrag(wcw  + (((cbw + j) * 8 + kb) << 9))
                            : gfrag(wcwh + (((cbw + j) * 8 + kb - 8) << 9));
    };
    auto FM = [&](bf16x8 (&A)[2], bf16x8 (&B)[4]) {
#pragma unroll
        for (int j = 0; j < 4; ++j) {
            acc[0][j] = MFMA(A[0], B[j], acc[0][j]);
            acc[1][j] = MFMA(A[1], B[j], acc[1][j]);
        }
    };
    PIPE3(16, LD, FM)
    char* eb = EB[w];
#pragma unroll
    for (int f = 0; f < 2; ++f)
#pragma unroll
        for (int j = 0; j < 4; ++j)
#pragma unroll
            for (int t = 0; t < 4; ++t) {
                int rl  = f * 16 + (l >> 4) * 4 + t;
                int row = row0 + wr + rl;
                int c   = col0 + wc + j * 16 + (l & 15);
                float zv = out[(size_t)row * HD + c];                 // zC
                float nv = tanhf(acc[f][j][t] + bih[512 + c] + bhh[512 + c]);
                float hv = h0[(size_t)row * HD + 512 + c];
                float hp = zv * hv + (1.0f - zv) * nv;
                hp = fminf(fmaxf(hp, -CLIPV), CLIPV);
                out[(size_t)row * HD + 512 + c] = hp;                 // con_state
                ldsw16(eb, rl, j * 16 + (l & 15), f2bf(hp));
            }
    EB_FENCE
#pragma unroll
    for (int rf = 0; rf < 2; ++rf)
#pragma unroll
        for (int kb2 = 0; kb2 < 2; ++kb2) {
            bf16x8 v = ldfrag(eb, rf * 16 + (l & 15), kb2, l >> 4);
            const int kbg = ((col0 + wc) >> 5) + kb2;
            *(bf16x8*)((char*)out + (size_t)((rb0 + rf) * 16 + 8 + kbg) * 5120
                       + 1024 + l * 16) = v;                          // cs
        }
}

// ================================= co ========================================
__global__ __launch_bounds__(256, 4) void k_co(
    const u16* __restrict__ ws, const float* __restrict__ cb_,
    float* out) {
    __shared__ char EB[4][4096];
    const int lb = xswz();
    const int col0 = (lb & 1) * 128;
    const int row0 = (lb >> 1) * 64;
    GIDX
    const int rb0 = (row0 + wr) >> 4;
    const int cbw = (col0 + wc) >> 4;
    const u16* wcow = ws + OFF_COW;
    const char* outb = (const char*)out;
    f32x4 acc[2][4] = {};
    bf16x8 A0[2], B0[4], A1[2], B1[4], A2[2], B2[4];
    auto LD = [&](int kb, bf16x8 (&A)[2], bf16x8 (&B)[4]) {
        A[0] = gldx4(outb + (size_t)(rb0 * 16 + 8 + kb) * 5120 + 1024 + l * 16);
        A[1] = gldx4(outb + (size_t)((rb0 + 1) * 16 + 8 + kb) * 5120 + 1024 + l * 16);
#pragma unroll
        for (int j = 0; j < 4; ++j)
            B[j] = gfrag(wcow + (((cbw + j) * 8 + kb) << 9));
    };
    auto FM = [&](bf16x8 (&A)[2], bf16x8 (&B)[4]) {
#pragma unroll
        for (int j = 0; j < 4; ++j) {
            acc[0][j] = MFMA(A[0], B[j], acc[0][j]);
            acc[1][j] = MFMA(A[1], B[j], acc[1][j]);
        }
    };
    PIPE3(8, LD, FM)
    char* eb = EB[w];
#pragma unroll
    for (int f = 0; f < 2; ++f)
#pragma unroll
        for (int j = 0; j < 4; ++j)
#pragma unroll
            for (int t = 0; t < 4; ++t) {
                int rl  = f * 16 + (l >> 4) * 4 + t;
                int row = row0 + wr + rl;
                int c   = col0 + wc + j * 16 + (l & 15);
                float v = acc[f][j][t] + cb_[c];
                if (col0 == 0) {                    // co_mean half
                    out[(size_t)row * HD + 1024 + c] = v;             // gen_input
                    out[(size_t)row * HD + 768 + c]  = v;             // mean
                    ldsw16(eb, rl, j * 16 + (l & 15), f2bf(v));
                } else {
                    out[(size_t)row * HD + 896 + (c - 128)] = v;      // logstd
                }
            }
    if (col0 == 0) {
        EB_FENCE
#pragma unroll
        for (int rf = 0; rf < 2; ++rf)
#pragma unroll
            for (int kb2 = 0; kb2 < 2; ++kb2) {
                bf16x8 v = ldfrag(eb, rf * 16 + (l & 15), kb2, l >> 4);
                const int kbg = (wc >> 5) + kb2;
                char* base = (char*)out + (size_t)((rb0 + rf) * 16 + kbg * 2) * 5120 + 4608;
                *(bf16x8*)(base + (l >> 5) * 5120 + (l & 31) * 16) = v;  // gi
            }
    }
}

// =============================== gen_rz ======================================
// grid 2048: gate = lb&1 (0=z,1=r), colblk = (lb>>1)&3, rp = lb>>3
__global__ __launch_bounds__(256, 4) void k_gen_rz(
    u16* __restrict__ ws, const float* __restrict__ h0,
    const float* __restrict__ bih, const float* __restrict__ bhh,
    float* out) {
    __shared__ char EB[4][4096];
    const int lb   = xswz();
    const int gate = lb & 1;
    const int col0 = ((lb >> 1) & 3) * 128;
    const int row0 = (lb >> 3) * 64;
    GIDX
    const int rb0 = (row0 + wr) >> 4;
    const int cbw = (gate ? 32 : 0) + ((col0 + wc) >> 4);
    const u16* wgwi = ws + OFF_GWI;
    const u16* wgwh = ws + OFF_GWH;
    const char* outb = (const char*)out;
    f32x4 acc[2][4] = {};
    bf16x8 A0[2], B0[4], A1[2], B1[4], A2[2], B2[4];
    auto LD = [&](int kb, bf16x8 (&A)[2], bf16x8 (&B)[4]) {
        if (kb < 4) {
            A[0] = gfrag2(outb + (size_t)(rb0 * 16 + kb * 2) * 5120 + 4608);
            A[1] = gfrag2(outb + (size_t)((rb0 + 1) * 16 + kb * 2) * 5120 + 4608);
        } else {
            A[0] = gfrag(PF(ws, rb0, kb - 4));
            A[1] = gfrag(PF(ws, rb0 + 1, kb - 4));
        }
#pragma unroll
        for (int j = 0; j < 4; ++j)
            B[j] = (kb < 4) ? gfrag(wgwi + (((cbw + j) * 4 + kb) << 9))
                            : gfrag(wgwh + (((cbw + j) * 16 + kb - 4) << 9));
    };
    auto FM = [&](bf16x8 (&A)[2], bf16x8 (&B)[4]) {
#pragma unroll
        for (int j = 0; j < 4; ++j) {
            acc[0][j] = MFMA(A[0], B[j], acc[0][j]);
            acc[1][j] = MFMA(A[1], B[j], acc[1][j]);
        }
    };
    PIPE3(20, LD, FM)
    if (gate) {                                     // r -> rhG frags (panel)
        char* eb = EB[w];
#pragma unroll
        for (int f = 0; f < 2; ++f)
#pragma unroll
            for (int j = 0; j < 4; ++j)
#pragma unroll
                for (int t = 0; t < 4; ++t) {
                    int rl  = f * 16 + (l >> 4) * 4 + t;
                    int row = row0 + wr + rl;
                    int c   = col0 + wc + j * 16 + (l & 15);
                    float rv = sigm(acc[f][j][t] + bih[512 + c] + bhh[512 + c]);
                    float hv = h0[(size_t)row * HD + c];
                    ldsw16(eb, rl, j * 16 + (l & 15), f2bf(rv * hv));
                }
        EB_FENCE
#pragma unroll
        for (int rf = 0; rf < 2; ++rf)
#pragma unroll
            for (int kb2 = 0; kb2 < 2; ++kb2) {
                bf16x8 v = ldfrag(eb, rf * 16 + (l & 15), kb2, l >> 4);
                const int kbg = ((col0 + wc) >> 5) + kb2;       // 0..15
                *(bf16x8*)((u16*)PF(ws, rb0 + rf, 16 + kbg) + l * 8) = v;
            }
    } else {                                        // z -> sigm f32 at out[0:512)
#pragma unroll
        for (int f = 0; f < 2; ++f)
#pragma unroll
            for (int j = 0; j < 4; ++j)
#pragma unroll
                for (int t = 0; t < 4; ++t) {
                    int row = row0 + wr + f * 16 + (l >> 4) * 4 + t;
                    int c   = col0 + wc + j * 16 + (l & 15);
                    out[(size_t)row * HD + c] = sigm(acc[f][j][t] + bih[c] + bhh[c]);
                }
    }
}

// =============================== gen_n =======================================
__global__ __launch_bounds__(256, 4) void k_gen_n(
    const u16* __restrict__ ws, const float* __restrict__ h0,
    const float* __restrict__ bih, const float* __restrict__ bhh,
    float* out) {
    const int lb   = xswz();
    const int col0 = (lb & 3) * 128;
    const int row0 = (lb >> 2) * 64;
    GIDX
    const int rb0 = (row0 + wr) >> 4;
    const int cbw = 64 + ((col0 + wc) >> 4);
    const u16* wgwi = ws + OFF_GWI;
    const u16* wgwh = ws + OFF_GWH;
    const char* outb = (const char*)out;
    f32x4 acc[2][4] = {};
    bf16x8 A0[2], B0[4], A1[2], B1[4], A2[2], B2[4];
    auto LD = [&](int kb, bf16x8 (&A)[2], bf16x8 (&B)[4]) {
        if (kb < 4) {
            A[0] = gfrag2(outb + (size_t)(rb0 * 16 + kb * 2) * 5120 + 4608);
            A[1] = gfrag2(outb + (size_t)((rb0 + 1) * 16 + kb * 2) * 5120 + 4608);
        } else {
            A[0] = gfrag(PF(ws, rb0, 16 + kb - 4));               // rhG
            A[1] = gfrag(PF(ws, rb0 + 1, 16 + kb - 4));
        }
#pragma unroll
        for (int j = 0; j < 4; ++j)
            B[j] = (kb < 4) ? gfrag(wgwi + (((cbw + j) * 4 + kb) << 9))
                            : gfrag(wgwh + (((cbw + j) * 16 + kb - 4) << 9));
    };
    auto FM = [&](bf16x8 (&A)[2], bf16x8 (&B)[4]) {
#pragma unroll
        for (int j = 0; j < 4; ++j) {
            acc[0][j] = MFMA(A[0], B[j], acc[0][j]);
            acc[1][j] = MFMA(A[1], B[j], acc[1][j]);
        }
    };
    PIPE3(20, LD, FM)
#pragma unroll
    for (int f = 0; f < 2; ++f)
#pragma unroll
        for (int j = 0; j < 4; ++j)
#pragma unroll
            for (int t = 0; t < 4; ++t) {
                int row = row0 + wr + f * 16 + (l >> 4) * 4 + t;
                int c   = col0 + wc + j * 16 + (l & 15);
                float zv = out[(size_t)row * HD + c];             // zG
                float nv = tanhf(acc[f][j][t] + bih[1024 + c] + bhh[1024 + c]);
                float hv = h0[(size_t)row * HD + c];
                float hp = zv * hv + (1.0f - zv) * nv;
                out[(size_t)row * HD + c] = fminf(fmaxf(hp, -CLIPV), CLIPV);
            }
}

// ===================== LDS gemm1 machinery (fac + fallback) =================
__device__ __forceinline__ void gll16(const void* g, void* l) {
    __builtin_amdgcn_global_load_lds((const __attribute__((address_space(1))) void*)g,
                                     (__attribute__((address_space(3))) void*)l,
                                     16, 0, 0);
}

struct KSrc {
    const void* p[5];
    int ld[5];
    int kind[5];
    const float* scale;
};

template <int R>
__device__ __forceinline__ void stage_issue(char* tile, const KSrc& S, int rbase,
                                            int k0, int sIdx, float* regs) {
    const int tid = threadIdx.x;
    if (S.kind[sIdx]) {
        const char* base = (const char*)S.p[sIdx];
        const int w = tid >> 6;
        const size_t ld = (size_t)S.ld[sIdx];
#pragma unroll
        for (int e = 0; e < R / 32; ++e) {
            const int q = e * 256 + tid;
            const int r = q >> 3;
            const int b = ((q & 7) << 4) ^ ((r & 7) << 4);
            gll16(base + ((size_t)(rbase + r) * ld + k0) * 2 + b, tile + e * 4096 + w * 1024);
        }
    } else {
        const float* base = (const float*)S.p[sIdx];
        const size_t ld = (size_t)S.ld[sIdx];
#pragma unroll
        for (int e = 0; e < R / 64; ++e) {
            const int q = e * 256 + tid;
            const int r = q >> 2;
            const int kloc = (q & 3) << 4;
            const float* pp = base + (size_t)(rbase + r) * ld + k0 + kloc;
            float* d = regs + e * 16;
            *(float4*)(d + 0)  = *(const float4*)(pp + 0);
            *(float4*)(d + 4)  = *(const float4*)(pp + 4);
            *(float4*)(d + 8)  = *(const float4*)(pp + 8);
            *(float4*)(d + 12) = *(const float4*)(pp + 12);
        }
    }
}

template <int R>
__device__ __forceinline__ void stage_write(char* tile, const KSrc& S, int rbase,
                                            int k0, int sIdx, float* regs) {
    if (S.kind[sIdx]) return;
    const int tid = threadIdx.x;
#pragma unroll
    for (int e = 0; e < R / 64; ++e) {
        const int q = e * 256 + tid;
        const int r = q >> 2;
        float* ff = regs + e * 16;
        if (S.scale) {
            const int kabs = k0 + ((q & 3) << 4);
#pragma unroll
            for (int j = 0; j < 16; ++j) ff[j] *= S.scale[kabs + j];
        }
        s16x8 v0, v1;
#pragma unroll
        for (int j = 0; j < 8; ++j) {
            v0[j] = (short)f2bf(ff[j]);
            v1[j] = (short)f2bf(ff[j + 8]);
        }
        const int swz = (r & 7) << 4;
        *(s16x8*)(tile + r * 128 + ((((q & 3) << 5) + 0)  ^ swz)) = v0;
        *(s16x8*)(tile + r * 128 + ((((q & 3) << 5) + 16) ^ swz)) = v1;
    }
}

__device__ __forceinline__ void cmp64_4w(f32x4 (&acc)[2][4], const char* At, const char* Wt) {
    const int l = threadIdx.x & 63, w = threadIdx.x >> 6;
    const int wr = (w >> 1) << 5, wc = (w & 1) << 6;
    const int g = l >> 4, r15 = l & 15;
#pragma unroll
    for (int ks = 0; ks < 2; ++ks) {
        bf16x8 a[2], b[4];
#pragma unroll
        for (int f = 0; f < 2; ++f) a[f] = ldfrag(At, wr + f * 16 + r15, ks, g);
#pragma unroll
        for (int f = 0; f < 4; ++f) b[f] = ldfrag(Wt, wc + f * 16 + r15, ks, g);
#pragma unroll
        for (int i = 0; i < 2; ++i)
#pragma unroll
            for (int j = 0; j < 4; ++j)
                acc[i][j] = MFMA(a[i], b[j], acc[i][j]);
    }
}

template <int NT>
__device__ __forceinline__ void gemm1(f32x4 (&acc)[2][4], char* At, char* Wt,
                                      const KSrc& A, const KSrc& W,
                                      int row0, int col0) {
    float ra[16], rw[32];
#pragma unroll
    for (int kt = 0; kt < NT; ++kt) {
        const int s = kt >> 1;
        __syncthreads();
        stage_issue<64> (At, A, row0, kt * 64, s, ra);
        stage_issue<128>(Wt, W, col0, kt * 64, s, rw);
        stage_write<64> (At, A, row0, kt * 64, s, ra);
        stage_write<128>(Wt, W, col0, kt * 64, s, rw);
        __syncthreads();
        cmp64_4w(acc, At, Wt);
    }
}

#define FB_SHARED __shared__ alignas(16) char At[8192], Wt[16384];
#define FB_IDX                                                              \
    const int l  = threadIdx.x & 63;                                        \
    const int w  = threadIdx.x >> 6;                                        \
    const int wr = (w >> 1) << 5;                                           \
    const int wc = (w & 1) << 6;

// ------------------------------ fac (PRE) ------------------------------------
__global__ __launch_bounds__(256) void k_facp(
    const u16* __restrict__ ws, float* __restrict__ out) {
    FB_SHARED
    const int row0 = xswz() * 64;
    KSrc A = {{out, out, out, out, nullptr},
              {HD, HD, HD, HD, 0}, {0, 0, 0, 0, 0}, nullptr};
    KSrc W = {{ws + OFF_FW, ws + OFF_FW, ws + OFF_FW, ws + OFF_FW, nullptr},
              {512, 512, 512, 512, 0}, {1, 1, 1, 1, 0}, nullptr};
    f32x4 acc[2][4] = {};
    gemm1<8>(acc, At, Wt, A, W, row0, 0);
    FB_IDX
#pragma unroll
    for (int i = 0; i < 2; ++i)
#pragma unroll
        for (int j = 0; j < 4; ++j)
#pragma unroll
            for (int t = 0; t < 4; ++t) {
                int row = row0 + wr + i * 16 + (l >> 4) * 4 + t;
                int c   = wc + j * 16 + (l & 15);
                out[(size_t)row * HD + 1152 + c] = acc[i][j][t];
            }
}

// ===================== fallback path (no usable ws) =========================
__global__ __launch_bounds__(256) void f_con_r(
    const float* __restrict__ x, const float* __restrict__ h0,
    const float* __restrict__ wih, const float* __restrict__ bih,
    const float* __restrict__ whh, const float* __restrict__ bhh,
    float* __restrict__ out) {
    FB_SHARED
    const int lb = xswz();
    const int col0 = (lb & 1) * 128;
    const int row0 = (lb >> 1) * 64;
    KSrc A = {{x, h0 + 1024, h0 + 256, h0 + 256, nullptr},
              {128, HD, HD, HD, 0}, {0, 0, 0, 0, 0}, nullptr};
    KSrc W = {{wih + 65536, wih + 65536, whh + 65536 - 256, whh + 65536 - 256, nullptr},
              {256, 256, 256, 256, 0}, {0, 0, 0, 0, 0}, nullptr};
    f32x4 acc[2][4] = {};
    gemm1<8>(acc, At, Wt, A, W, row0, col0);
    FB_IDX
    u16* outs = (u16*)out;
#pragma unroll
    for (int i = 0; i < 2; ++i)
#pragma unroll
        for (int j = 0; j < 4; ++j)
#pragma unroll
            for (int t = 0; t < 4; ++t) {
                int row = row0 + wr + i * 16 + (l >> 4) * 4 + t;
                int c   = col0 + wc + j * 16 + (l & 15);
                float rv = sigm(acc[i][j][t] + bih[256 + c] + bhh[256 + c]);
                float hv = h0[(size_t)row * HD + 512 + c];
                outs[(size_t)row * 2560 + 512 + c] = f2bf(rv * hv);
            }
}

__global__ __launch_bounds__(256) void f_con_zn(
    const float* __restrict__ x, const float* __restrict__ h0,
    const float* __restrict__ wih, const float* __restrict__ bih,
    const float* __restrict__ whh, const float* __restrict__ bhh,
    float* __restrict__ out) {
    FB_SHARED
    const int lb = xswz();
    const int col0 = (lb & 1) * 128;
    const int row0 = (lb >> 1) * 64;
    const u16* outs = (const u16*)out;
    KSrc Az = {{x, h0 + 1024, h0 + 256, h0 + 256, nullptr},
               {128, HD, HD, HD, 0}, {0, 0, 0, 0, 0}, nullptr};
    KSrc Wz = {{wih, wih, whh - 256, whh - 256, nullptr},
               {256, 256, 256, 256, 0}, {0, 0, 0, 0, 0}, nullptr};
    KSrc An = {{x, h0 + 1024, outs + 256, outs + 256, nullptr},
               {128, HD, 2560, 2560, 0}, {0, 0, 1, 1, 0}, nullptr};
    KSrc Wn = {{wih + 512 * 256, wih + 512 * 256,
                whh + 512 * 256 - 256, whh + 512 * 256 - 256, nullptr},
               {256, 256, 256, 256, 0}, {0, 0, 0, 0, 0}, nullptr};
    f32x4 aZ[2][4] = {}, aN[2][4] = {};
    gemm1<8>(aZ, At, Wt, Az, Wz, row0, col0);
    gemm1<8>(aN, At, Wt, An, Wn, row0, col0);
    FB_IDX
#pragma unroll
    for (int i = 0; i < 2; ++i)
#pragma unroll
        for (int j = 0; j < 4; ++j)
#pragma unroll
            for (int t = 0; t < 4; ++t) {
                int row = row0 + wr + i * 16 + (l >> 4) * 4 + t;
                int c   = col0 + wc + j * 16 + (l & 15);
                float zv = sigm(aZ[i][j][t] + bih[c] + bhh[c]);
                float nv = tanhf(aN[i][j][t] + bih[512 + c] + bhh[512 + c]);
                float hv = h0[(size_t)row * HD + 512 + c];
                float hp = zv * hv + (1.0f - zv) * nv;
                out[(size_t)row * HD + 512 + c] = fminf(fmaxf(hp, -CLIPV), CLIPV);
            }
}

__global__ __launch_bounds__(256) void f_co(
    const float* __restrict__ cw, const float* __restrict__ cb,
    float* __restrict__ out) {
    FB_SHARED
    const int lb = xswz();
    const int col0 = (lb & 1) * 128;
    const int row0 = (lb >> 1) * 64;
    KSrc A = {{out + 512, out + 512, nullptr, nullptr, nullptr},
              {HD, HD, 0, 0, 0}, {0, 0, 0, 0, 0}, nullptr};
    KSrc W = {{cw, cw, nullptr, nullptr, nullptr},
              {256, 256, 0, 0, 0}, {0, 0, 0, 0, 0}, nullptr};
    f32x4 acc[2][4] = {};
    gemm1<4>(acc, At, Wt, A, W, row0, col0);
    FB_IDX
    u16* outw = (u16*)out;
#pragma unroll
    for (int i = 0; i < 2; ++i)
#pragma unroll
        for (int j = 0; j < 4; ++j)
#pragma unroll
            for (int t = 0; t < 4; ++t) {
                int row = row0 + wr + i * 16 + (l >> 4) * 4 + t;
                int c   = col0 + wc + j * 16 + (l & 15);
                float v = acc[i][j][t] + cb[c];
                if (c < 128) {
                    out[(size_t)row * HD + 1024 + c]    = v;
                    outw[(size_t)row * 2560 + 2304 + c] = f2bf(v);
                }
            }
}

__global__ __launch_bounds__(256) void f_gen_r(
    const float* __restrict__ h0,
    const float* __restrict__ wih, const float* __restrict__ bih,
    const float* __restrict__ whh, const float* __restrict__ bhh,
    float* __restrict__ out) {
    FB_SHARED
    const int lb = xswz();
    const int col0 = (lb & 3) * 128;
    const int row0 = (lb >> 2) * 64;
    const u16* outs = (const u16*)out;
    KSrc A = {{outs + 2304, h0 - 128, h0 - 128, h0 - 128, h0 - 128},
              {2560, HD, HD, HD, HD}, {1, 0, 0, 0, 0}, nullptr};
    KSrc W = {{wih + 65536, whh + 512 * 512 - 128, whh + 512 * 512 - 128,
               whh + 512 * 512 - 128, whh + 512 * 512 - 128},
              {128, 512, 512, 512, 512}, {0, 0, 0, 0, 0}, nullptr};
    f32x4 acc[2][4] = {};
    gemm1<10>(acc, At, Wt, A, W, row0, col0);
    FB_IDX
    u16* outw = (u16*)out;
#pragma unroll
    for (int i = 0; i < 2; ++i)
#pragma unroll
        for (int j = 0; j < 4; ++j)
#pragma unroll
            for (int t = 0; t < 4; ++t) {
                int row = row0 + wr + i * 16 + (l >> 4) * 4 + t;
                int c   = col0 + wc + j * 16 + (l & 15);
                float rv = sigm(acc[i][j][t] + bih[512 + c] + bhh[512 + c]);
                float hv = h0[(size_t)row * HD + c];
                outw[(size_t)row * 2560 + 1536 + c] = f2bf(rv * hv);
            }
}

__global__ __launch_bounds__(256) void f_gen_zn(
    const float* __restrict__ h0,
    const float* __restrict__ wih, const float* __restrict__ bih,
    const float* __restrict__ whh, const float* __restrict__ bhh,
    float* __restrict__ out) {
    FB_SHARED
    const int lb = xswz();
    const int col0 = (lb & 3) * 128;
    const int row0 = (lb >> 2) * 64;
    const u16* outs = (const u16*)out;
    KSrc Az = {{outs + 2304, h0 - 128, h0 - 128, h0 - 128, h0 - 128},
               {2560, HD, HD, HD, HD}, {1, 0, 0, 0, 0}, nullptr};
    KSrc Wz = {{wih, whh - 128, whh - 128, whh - 128, whh - 128},
               {128, 512, 512, 512, 512}, {0, 0, 0, 0, 0}, nullptr};
    KSrc An = {{outs + 2304, outs + 1408, outs + 1408, outs + 1408, outs + 1408},
               {2560, 2560, 2560, 2560, 2560}, {1, 1, 1, 1, 1}, nullptr};
    KSrc Wn = {{wih + 1024 * 128, whh + 1024 * 512 - 128, whh + 1024 * 512 - 128,
                whh + 1024 * 512 - 128, whh + 1024 * 512 - 128},
               {128, 512, 512, 512, 512}, {0, 0, 0, 0, 0}, nullptr};
    f32x4 aZ[2][4] = {}, aN[2][4] = {};
    gemm1<10>(aZ, At, Wt, Az, Wz, row0, col0);
    gemm1<10>(aN, At, Wt, An, Wn, row0, col0);
    FB_IDX
#pragma unroll
    for (int i = 0; i < 2; ++i)
#pragma unroll
        for (int j = 0; j < 4; ++j)
#pragma unroll
            for (int t = 0; t < 4; ++t) {
                int row = row0 + wr + i * 16 + (l >> 4) * 4 + t;
                int c   = col0 + wc + j * 16 + (l & 15);
                float zv = sigm(aZ[i][j][t] + bih[c] + bhh[c]);
                float nv = tanhf(aN[i][j][t] + bih[1024 + c] + bhh[1024 + c]);
                float hv = h0[(size_t)row * HD + c];
                float hp = zv * hv + (1.0f - zv) * nv;
                out[(size_t)row * HD + c] = fminf(fmaxf(hp, -CLIPV), CLIPV);
            }
}

__global__ __launch_bounds__(256) void f_fac(
    const float* __restrict__ fw, float* __restrict__ out) {
    FB_SHARED
    __shared__ float invn[512];
    const int row0 = xswz() * 64;
    {
        const int t = threadIdx.x;
        float s0 = 0.f, s1 = 0.f;
        for (int r = 0; r < 128; ++r) {
            float a0 = fw[r * 512 + t];
            float a1 = fw[r * 512 + t + 256];
            s0 = fmaf(a0, a0, s0);
            s1 = fmaf(a1, a1, s1);
        }
        invn[t]       = 1.0f / fmaxf(sqrtf(s0), 1e-12f);
        invn[t + 256] = 1.0f / fmaxf(sqrtf(s1), 1e-12f);
        __syncthreads();
    }
    KSrc A = {{out, out, out, out, nullptr},
              {HD, HD, HD, HD, 0}, {0, 0, 0, 0, 0}, nullptr};
    KSrc W = {{fw, fw, fw, fw, nullptr},
              {512, 512, 512, 512, 0}, {0, 0, 0, 0, 0}, invn};
    f32x4 acc[2][4] = {};
    gemm1<8>(acc, At, Wt, A, W, row0, 0);
    FB_IDX
#pragma unroll
    for (int i = 0; i < 2; ++i)
#pragma unroll
        for (int j = 0; j < 4; ++j)
#pragma unroll
            for (int t = 0; t < 4; ++t) {
                int row = row0 + wr + i * 16 + (l >> 4) * 4 + t;
                int c   = wc + j * 16 + (l & 15);
                out[(size_t)row * HD + 1152 + c] = acc[i][j][t];
            }
}

__global__ __launch_bounds__(256) void f_co_fin(
    const float* __restrict__ cw, const float* __restrict__ cb,
    float* __restrict__ out) {
    FB_SHARED
    const int row0 = xswz() * 64;
    KSrc A = {{out + 512, out + 512, nullptr, nullptr, nullptr},
              {HD, HD, 0, 0, 0}, {0, 0, 0, 0, 0}, nullptr};
    KSrc W = {{cw + 128 * 256, cw + 128 * 256, nullptr, nullptr, nullptr},
              {256, 256, 0, 0, 0}, {0, 0, 0, 0, 0}, nullptr};
    f32x4 acc[2][4] = {};
    gemm1<4>(acc, At, Wt, A, W, row0, 0);
    FB_IDX
#pragma unroll
    for (int i = 0; i < 2; ++i)
#pragma unroll
        for (int j = 0; j < 4; ++j)
#pragma unroll
            for (int t = 0; t < 4; ++t) {
                int row = row0 + wr + i * 16 + (l >> 4) * 4 + t;
                int c   = wc + j * 16 + (l & 15);
                out[(size_t)row * HD + 896 + c] = acc[i][j][t] + cb[128 + c];
            }
#pragma unroll
    for (int e = 0; e < 8; ++e) {
        int idx = threadIdx.x + e * 256;
        int r   = idx >> 5;
        int cc  = (idx & 31) << 2;
        *(float4*)&out[(size_t)(row0 + r) * HD + 768 + cc] =
            *(const float4*)&out[(size_t)(row0 + r) * HD + 1024 + cc];
    }
}

// ------------------------------- launch -------------------------------------
extern "C" void kernel_launch(void* const* d_in, const int* in_sizes, int n_in,
                              void* d_out, int out_size, void* d_ws, size_t ws_size,
                              hipStream_t stream) {
    const float* x    = (const float*)d_in[0];
    const float* h0   = (const float*)d_in[1];
    const float* cwih = (const float*)d_in[2];
    const float* cbih = (const float*)d_in[3];
    const float* cwhh = (const float*)d_in[4];
    const float* cbhh = (const float*)d_in[5];
    const float* cow  = (const float*)d_in[6];
    const float* cob  = (const float*)d_in[7];
    const float* gwih = (const float*)d_in[8];
    const float* gbih = (const float*)d_in[9];
    const float* gwhh = (const float*)d_in[10];
    const float* gbhh = (const float*)d_in[11];
    const float* fw   = (const float*)d_in[12];
    float* out = (float*)d_out;
    u16* ws = (u16*)d_ws;

    const bool pre = (ws_size >= (size_t)WS_ELEMS * 2);
    if (pre) {
        k_pre_hf<<<8192, 256, 0, stream>>>(x, h0, ws);
        k_pre_wf<<<704,  256, 0, stream>>>(cwih, cwhh, cow, gwih, gwhh, ws + OFF_CW);
        k_pre_fw<<<2,    256, 0, stream>>>(fw, ws + OFF_FW);
        k_con_rz<<<1024, 256, 0, stream>>>(ws, h0, cbih, cbhh, out);
        k_con_n <<<512,  256, 0, stream>>>(ws, h0, cbih, cbhh, out);
        k_co    <<<512,  256, 0, stream>>>(ws, cob, out);
        k_gen_rz<<<2048, 256, 0, stream>>>(ws, h0, gbih, gbhh, out);
        k_gen_n <<<1024, 256, 0, stream>>>(ws, h0, gbih, gbhh, out);
        k_facp  <<<256,  256, 0, stream>>>(ws, out);
    } else {
        f_con_r <<<512,  256, 0, stream>>>(x, h0, cwih, cbih, cwhh, cbhh, out);
        f_con_zn<<<512,  256, 0, stream>>>(x, h0, cwih, cbih, cwhh, cbhh, out);
        f_co    <<<512,  256, 0, stream>>>(cow, cob, out);
        f_gen_r <<<1024, 256, 0, stream>>>(h0, gwih, gbih, gwhh, gbhh, out);
        f_gen_zn<<<1024, 256, 0, stream>>>(h0, gwih, gbih, gwhh, gbhh, out);
        f_fac   <<<256,  256, 0, stream>>>(fw, out);
        f_co_fin<<<256,  256, 0, stream>>>(cow, cob, out);
    }
}